// Round 3
// baseline (3226.645 us; speedup 1.0000x reference)
//
#include <hip/hip_runtime.h>
#include <stdint.h>

#define BB 8
#define NN 2048
#define DD 64
#define REGv 0.1f
#define NUM_ITERS 50
#define EPS_NORM 1e-8f
#define EPS_SINK 1e-10f
#define GRID_P 256u
#define NBAR 128

__device__ __forceinline__ float dot4(float4 a, float4 b) {
    return a.x * b.x + a.y * b.y + a.z * b.z + a.w * b.w;
}
__device__ __forceinline__ float4 fma4(float u, float4 k, float4 s) {
    s.x += u * k.x; s.y += u * k.y; s.z += u * k.z; s.w += u * k.w; return s;
}

// ---------------- init: maxd2 = 0, barrier counters = 0 ----------------
__global__ void init_k(unsigned* maxd, unsigned* bar) {
    int t = threadIdx.x;
    if (t < BB) maxd[t] = 0u;
    if (t < NBAR) bar[t] = 0u;
}

// ---------------- row squared norms (one wave per row) ----------------
__global__ void sq_k(const float* __restrict__ x0, const float* __restrict__ x1,
                     float* __restrict__ sq0, float* __restrict__ sq1) {
    int w = (blockIdx.x * 256 + threadIdx.x) >> 6;
    int lane = threadIdx.x & 63;
    if (w >= 2 * BB * NN) return;
    const float* src = (w < BB * NN) ? x0 : x1;
    int r = (w < BB * NN) ? w : w - BB * NN;
    float val = src[(size_t)r * DD + lane];
    float s = val * val;
    #pragma unroll
    for (int off = 32; off; off >>= 1) s += __shfl_xor(s, off);
    if (lane == 0) ((w < BB * NN) ? sq0 : sq1)[r] = s;
}

// ---------------- fused cdist: WRITE=0 -> max(d2); WRITE=1 -> K=exp ----------------
template<int WRITE>
__global__ __launch_bounds__(256) void distc_k(const float* __restrict__ x0,
                                               const float* __restrict__ x1,
                                               const float* __restrict__ sq0,
                                               const float* __restrict__ sq1,
                                               float* __restrict__ Kd,
                                               unsigned* __restrict__ maxd) {
    __shared__ float x0s[128 * 68];
    __shared__ float x1t[64 * 68];
    __shared__ float wred[4];
    int bid = blockIdx.x;
    int b = bid >> 9;
    int tile = bid & 511;
    int ti = tile >> 5, tj = tile & 31;
    int i0 = ti * 128, j0 = tj * 64;
    int t = threadIdx.x;

    const float4* g0 = (const float4*)(x0 + ((size_t)b * NN + i0) * DD);
    #pragma unroll
    for (int rep = 0; rep < 8; rep++) {
        int e = rep * 256 + t;
        int row = e >> 4, c4 = e & 15;
        *(float4*)&x0s[row * 68 + c4 * 4] = g0[row * 16 + c4];
    }
    const float4* g1 = (const float4*)(x1 + ((size_t)b * NN + j0) * DD);
    #pragma unroll
    for (int rep = 0; rep < 4; rep++) {
        int e = rep * 256 + t;
        int row = e >> 4, c4 = e & 15;
        float4 a = g1[row * 16 + c4];
        x1t[(c4 * 4 + 0) * 68 + row] = a.x;
        x1t[(c4 * 4 + 1) * 68 + row] = a.y;
        x1t[(c4 * 4 + 2) * 68 + row] = a.z;
        x1t[(c4 * 4 + 3) * 68 + row] = a.w;
    }
    __syncthreads();

    int tx = t & 15, ty = t >> 4;
    float4 acc4[8];
    #pragma unroll
    for (int di = 0; di < 8; di++) acc4[di] = make_float4(0.f, 0.f, 0.f, 0.f);

    #pragma unroll
    for (int k4 = 0; k4 < 16; k4++) {
        float4 b0 = *(const float4*)&x1t[(k4 * 4 + 0) * 68 + tx * 4];
        float4 b1 = *(const float4*)&x1t[(k4 * 4 + 1) * 68 + tx * 4];
        float4 b2 = *(const float4*)&x1t[(k4 * 4 + 2) * 68 + tx * 4];
        float4 b3 = *(const float4*)&x1t[(k4 * 4 + 3) * 68 + tx * 4];
        #pragma unroll
        for (int di = 0; di < 8; di++) {
            float4 a = *(const float4*)&x0s[(ty * 8 + di) * 68 + k4 * 4];
            acc4[di].x += a.x * b0.x + a.y * b1.x + a.z * b2.x + a.w * b3.x;
            acc4[di].y += a.x * b0.y + a.y * b1.y + a.z * b2.y + a.w * b3.y;
            acc4[di].z += a.x * b0.z + a.y * b1.z + a.z * b2.z + a.w * b3.z;
            acc4[di].w += a.x * b0.w + a.y * b1.w + a.z * b2.w + a.w * b3.w;
        }
    }

    int ib = b * NN + i0 + ty * 8;
    float4 s1 = *(const float4*)&sq1[b * NN + j0 + tx * 4];

    if (WRITE) {
        float mv = sqrtf(__uint_as_float(maxd[b])) + EPS_NORM;
        #pragma unroll
        for (int di = 0; di < 8; di++) {
            float s0 = sq0[ib + di];
            float4 o;
            o.x = expf(-((sqrtf(fmaxf(s0 + s1.x - 2.f * acc4[di].x, 0.f)) / mv) / REGv));
            o.y = expf(-((sqrtf(fmaxf(s0 + s1.y - 2.f * acc4[di].y, 0.f)) / mv) / REGv));
            o.z = expf(-((sqrtf(fmaxf(s0 + s1.z - 2.f * acc4[di].z, 0.f)) / mv) / REGv));
            o.w = expf(-((sqrtf(fmaxf(s0 + s1.w - 2.f * acc4[di].w, 0.f)) / mv) / REGv));
            *(float4*)&Kd[(size_t)(ib + di) * NN + j0 + tx * 4] = o;
        }
    } else {
        float lm = 0.0f;
        #pragma unroll
        for (int di = 0; di < 8; di++) {
            float s0 = sq0[ib + di];
            lm = fmaxf(lm, fmaxf(s0 + s1.x - 2.f * acc4[di].x, 0.f));
            lm = fmaxf(lm, fmaxf(s0 + s1.y - 2.f * acc4[di].y, 0.f));
            lm = fmaxf(lm, fmaxf(s0 + s1.z - 2.f * acc4[di].z, 0.f));
            lm = fmaxf(lm, fmaxf(s0 + s1.w - 2.f * acc4[di].w, 0.f));
        }
        #pragma unroll
        for (int off = 32; off; off >>= 1) lm = fmaxf(lm, __shfl_xor(lm, off));
        if ((t & 63) == 0) wred[t >> 6] = lm;
        __syncthreads();
        if (t == 0) {
            float m = fmaxf(fmaxf(wred[0], wred[1]), fmaxf(wred[2], wred[3]));
            atomicMax(&maxd[b], __float_as_uint(m));  // d2 >= 0: uint cmp == float cmp
        }
    }
}

// ---------------- hand-rolled grid barrier (256 co-resident blocks) ----------------
__device__ __forceinline__ void gbar(unsigned* c, int t) {
    __syncthreads();   // compiler drains vmcnt before s_barrier -> all block stores in L2
    if (t == 0) {
        __threadfence();                 // release: write back L2 (agent scope)
        atomicAdd(c, 1u);                // device-scope arrive
        while (__hip_atomic_load(c, __ATOMIC_RELAXED, __HIP_MEMORY_SCOPE_AGENT) < GRID_P)
            __builtin_amdgcn_s_sleep(1);
        __threadfence();                 // acquire: invalidate L1/L2
    }
    __syncthreads();
}

// ---------------- persistent Sinkhorn: K resident in VGPR+LDS for all 50 iters ----------------
// 256 blocks x 512 threads, 1 block/CU. Block q: batch b=q>>5, rows [g*64, g*64+64).
// Wave w owns rows w*8..w*8+7: rows 0-5 in 48 float4 VGPRs, rows 6-7 in LDS.
// Lane l owns columns j in {256k + 4l + m : k=0..7, m=0..3}.
__global__ __launch_bounds__(512, 2) void persist_k(const float* __restrict__ Kd,
                                                    float* __restrict__ partial,
                                                    float* __restrict__ vglob,
                                                    unsigned* __restrict__ bar,
                                                    int* __restrict__ out) {
    __shared__ float4 Kl4[16 * 512];   // 128 KB: 16 LDS-resident K rows
    __shared__ float4 vbuf4[512];      // 8 KB: v for this batch
    __shared__ float4 s0buf[512];      // 8 KB: sigma merge (waves 0-3) / vred scratch
    __shared__ float4 s1buf[512];      // 8 KB: sigma merge (waves 4-7)

    const int t = threadIdx.x;
    const int l = t & 63;
    const int w = t >> 6;
    const int q = blockIdx.x;
    const int b = q >> 5;
    const int g = q & 31;

    const float4* Kg = (const float4*)Kd + (size_t)(b * NN + g * 64 + w * 8) * 512;

    // stage LDS rows (r=6,7)
    #pragma unroll
    for (int rr = 0; rr < 2; rr++)
        #pragma unroll
        for (int k = 0; k < 8; k++)
            Kl4[(w * 2 + rr) * 512 + k * 64 + l] = Kg[(size_t)(6 + rr) * 512 + k * 64 + l];

    // stage register rows (r=0..5): 192 VGPRs
    float4 Kreg[6][8];
    #pragma unroll
    for (int r = 0; r < 6; r++)
        #pragma unroll
        for (int k = 0; k < 8; k++)
            Kreg[r][k] = Kg[(size_t)r * 512 + k * 64 + l];

    vbuf4[t] = make_float4(1.0f / NN, 1.0f / NN, 1.0f / NN, 1.0f / NN);

    const int kb6 = (w * 2) * 512 + l;
    const int kb7 = kb6 + 512;

    float u[8];

    for (int it = 0; it < NUM_ITERS; ++it) {
        __syncthreads();   // vbuf ready

        // ---- phase A: row dots -> u ----
        float dp[8] = {0, 0, 0, 0, 0, 0, 0, 0};
        #pragma unroll
        for (int k = 0; k < 8; k++) {
            float4 vk = vbuf4[k * 64 + l];
            float4 c6 = Kl4[kb6 + k * 64];
            float4 c7 = Kl4[kb7 + k * 64];
            #pragma unroll
            for (int r = 0; r < 6; r++) dp[r] += dot4(Kreg[r][k], vk);
            dp[6] += dot4(c6, vk);
            dp[7] += dot4(c7, vk);
            __builtin_amdgcn_sched_barrier(0);
        }
        #pragma unroll
        for (int r = 0; r < 8; r++) {
            float s = dp[r];
            #pragma unroll
            for (int off = 32; off; off >>= 1) s += __shfl_xor(s, off);
            u[r] = 1.0f / (s + EPS_SINK);
        }

        // ---- phase B: sigma[j] = sum_r u[r]*K[r,j] (lane-local j) ----
        float4 sg[8];
        #pragma unroll
        for (int k = 0; k < 8; k++) {
            float4 c6 = Kl4[kb6 + k * 64];
            float4 c7 = Kl4[kb7 + k * 64];
            float4 s = make_float4(0.f, 0.f, 0.f, 0.f);
            #pragma unroll
            for (int r = 0; r < 6; r++) s = fma4(u[r], Kreg[r][k], s);
            s = fma4(u[6], c6, s);
            s = fma4(u[7], c7, s);
            sg[k] = s;
            __builtin_amdgcn_sched_barrier(0);
        }

        // ---- merge 8 wave-sigmas: two 4-wave groups, serialized RMW ----
        float4* mybuf = (w < 4) ? s0buf : s1buf;
        const int ws = w & 3;
        #pragma unroll
        for (int step = 0; step < 4; step++) {
            if (ws == step) {
                #pragma unroll
                for (int k = 0; k < 8; k++) {
                    int idx = k * 64 + l;
                    float4 cur = (step == 0) ? make_float4(0.f, 0.f, 0.f, 0.f) : mybuf[idx];
                    cur.x += sg[k].x; cur.y += sg[k].y; cur.z += sg[k].z; cur.w += sg[k].w;
                    mybuf[idx] = cur;
                }
            }
            __syncthreads();
        }

        // ---- write block partial (8 KB) ----
        {
            float4 a = s0buf[t], c = s1buf[t];
            float4 pt = make_float4(a.x + c.x, a.y + c.y, a.z + c.z, a.w + c.w);
            ((float4*)partial)[(size_t)(b * 32 + g) * 512 + t] = pt;
        }
        gbar(&bar[2 * it], t);

        // ---- distributed v-reduce: block q -> 16 float4 of vglob ----
        {
            int c4 = g * 16 + (t & 15);
            int prow = t >> 4;     // 0..31
            float4 pv = ((const float4*)partial)[(size_t)(b * 32 + prow) * 512 + c4];
            #pragma unroll
            for (int off = 16; off <= 32; off <<= 1) {
                pv.x += __shfl_xor(pv.x, off);
                pv.y += __shfl_xor(pv.y, off);
                pv.z += __shfl_xor(pv.z, off);
                pv.w += __shfl_xor(pv.w, off);
            }
            if (l < 16) s0buf[w * 16 + l] = pv;
            __syncthreads();
            if (t < 16) {
                float4 s = s0buf[t];
                #pragma unroll
                for (int ww = 1; ww < 8; ww++) {
                    float4 o = s0buf[ww * 16 + t];
                    s.x += o.x; s.y += o.y; s.z += o.z; s.w += o.w;
                }
                float4 vv;
                vv.x = 1.0f / (s.x + EPS_SINK);
                vv.y = 1.0f / (s.y + EPS_SINK);
                vv.z = 1.0f / (s.z + EPS_SINK);
                vv.w = 1.0f / (s.w + EPS_SINK);
                ((float4*)vglob)[q * 16 + t] = vv;
            }
        }
        gbar(&bar[2 * it + 1], t);

        // ---- reload v for this batch ----
        vbuf4[t] = ((const float4*)vglob)[b * 512 + t];
    }
    __syncthreads();

    // ---- argmax of P = (u*K)*v per row (numpy first-occurrence tie-break) ----
    #pragma unroll
    for (int r = 0; r < 8; r++) {
        float best = -1.0f;
        int bi = 0;
        #pragma unroll
        for (int k = 0; k < 8; k++) {
            float4 vk = vbuf4[k * 64 + l];
            float4 kr;
            if (r < 6) kr = Kreg[r][k];
            else kr = Kl4[(r == 6 ? kb6 : kb7) + k * 64];
            float4 p;
            p.x = (u[r] * kr.x) * vk.x;
            p.y = (u[r] * kr.y) * vk.y;
            p.z = (u[r] * kr.z) * vk.z;
            p.w = (u[r] * kr.w) * vk.w;
            int j0 = k * 256 + l * 4;
            if (p.x > best) { best = p.x; bi = j0; }
            if (p.y > best) { best = p.y; bi = j0 + 1; }
            if (p.z > best) { best = p.z; bi = j0 + 2; }
            if (p.w > best) { best = p.w; bi = j0 + 3; }
        }
        #pragma unroll
        for (int off = 32; off; off >>= 1) {
            float ov = __shfl_xor(best, off);
            int oi = __shfl_xor(bi, off);
            if (ov > best || (ov == best && oi < bi)) { best = ov; bi = oi; }
        }
        if (l == 0) out[b * NN + g * 64 + w * 8 + r] = bi;
    }
}

extern "C" void kernel_launch(void* const* d_in, const int* in_sizes, int n_in,
                              void* d_out, int out_size, void* d_ws, size_t ws_size,
                              hipStream_t stream) {
    const float* x0 = (const float*)d_in[0];
    const float* x1 = (const float*)d_in[1];
    int* out = (int*)d_out;
    char* ws = (char*)d_ws;

    // ws layout (bytes)
    float* Kd      = (float*)(ws + 0ull);                 // 134217728
    float* partial = (float*)(ws + 134217728ull);         // 2097152 (8 x 32 x 2048 f32)
    float* vglob   = (float*)(ws + 136314880ull);         // 65536
    float* sq0     = (float*)(ws + 136380416ull);         // 65536
    float* sq1     = (float*)(ws + 136445952ull);         // 65536
    unsigned* maxd = (unsigned*)(ws + 136511488ull);      // 32
    unsigned* bar  = (unsigned*)(ws + 136511520ull);      // 512

    init_k<<<1, 256, 0, stream>>>(maxd, bar);
    sq_k<<<8192, 256, 0, stream>>>(x0, x1, sq0, sq1);
    distc_k<0><<<4096, 256, 0, stream>>>(x0, x1, sq0, sq1, Kd, maxd);
    distc_k<1><<<4096, 256, 0, stream>>>(x0, x1, sq0, sq1, Kd, maxd);
    persist_k<<<256, 512, 0, stream>>>(Kd, partial, vglob, bar, out);
}

// Round 5
// 2755.788 us; speedup vs baseline: 1.1709x; 1.1709x over previous
//
#include <hip/hip_runtime.h>
#include <stdint.h>

#define BB 8
#define NN 2048
#define DD 64
#define REGv 0.1f
#define NUM_ITERS 50
#define EPS_NORM 1e-8f
#define EPS_SINK 1e-10f
#define GRID_P 256u
#define NBAR 128

typedef float f4 __attribute__((ext_vector_type(4)));
#define KEEP(x) asm volatile("" : "+v"(x))

__device__ __forceinline__ float dotf4(f4 a, f4 b) {
    return a.x * b.x + a.y * b.y + a.z * b.z + a.w * b.w;
}
__device__ __forceinline__ f4 fmaf4(float u, f4 k, f4 s) { return s + u * k; }

// ---------------- init: maxd2 = 0, barrier counters = 0 ----------------
__global__ void init_k(unsigned* maxd, unsigned* bar) {
    int t = threadIdx.x;
    if (t < BB) maxd[t] = 0u;
    if (t < NBAR) bar[t] = 0u;
}

// ---------------- row squared norms (one wave per row) ----------------
__global__ void sq_k(const float* __restrict__ x0, const float* __restrict__ x1,
                     float* __restrict__ sq0, float* __restrict__ sq1) {
    int w = (blockIdx.x * 256 + threadIdx.x) >> 6;
    int lane = threadIdx.x & 63;
    if (w >= 2 * BB * NN) return;
    const float* src = (w < BB * NN) ? x0 : x1;
    int r = (w < BB * NN) ? w : w - BB * NN;
    float val = src[(size_t)r * DD + lane];
    float s = val * val;
    #pragma unroll
    for (int off = 32; off; off >>= 1) s += __shfl_xor(s, off);
    if (lane == 0) ((w < BB * NN) ? sq0 : sq1)[r] = s;
}

// ---------------- fused cdist: WRITE=0 -> max(d2); WRITE=1 -> K=exp ----------------
template<int WRITE>
__global__ __launch_bounds__(256) void distc_k(const float* __restrict__ x0,
                                               const float* __restrict__ x1,
                                               const float* __restrict__ sq0,
                                               const float* __restrict__ sq1,
                                               float* __restrict__ Kd,
                                               unsigned* __restrict__ maxd) {
    __shared__ float x0s[128 * 68];
    __shared__ float x1t[64 * 68];
    __shared__ float wred[4];
    int bid = blockIdx.x;
    int b = bid >> 9;
    int tile = bid & 511;
    int ti = tile >> 5, tj = tile & 31;
    int i0 = ti * 128, j0 = tj * 64;
    int t = threadIdx.x;

    const float4* g0 = (const float4*)(x0 + ((size_t)b * NN + i0) * DD);
    #pragma unroll
    for (int rep = 0; rep < 8; rep++) {
        int e = rep * 256 + t;
        int row = e >> 4, c4 = e & 15;
        *(float4*)&x0s[row * 68 + c4 * 4] = g0[row * 16 + c4];
    }
    const float4* g1 = (const float4*)(x1 + ((size_t)b * NN + j0) * DD);
    #pragma unroll
    for (int rep = 0; rep < 4; rep++) {
        int e = rep * 256 + t;
        int row = e >> 4, c4 = e & 15;
        float4 a = g1[row * 16 + c4];
        x1t[(c4 * 4 + 0) * 68 + row] = a.x;
        x1t[(c4 * 4 + 1) * 68 + row] = a.y;
        x1t[(c4 * 4 + 2) * 68 + row] = a.z;
        x1t[(c4 * 4 + 3) * 68 + row] = a.w;
    }
    __syncthreads();

    int tx = t & 15, ty = t >> 4;
    float4 acc4[8];
    #pragma unroll
    for (int di = 0; di < 8; di++) acc4[di] = make_float4(0.f, 0.f, 0.f, 0.f);

    #pragma unroll
    for (int k4 = 0; k4 < 16; k4++) {
        float4 b0 = *(const float4*)&x1t[(k4 * 4 + 0) * 68 + tx * 4];
        float4 b1 = *(const float4*)&x1t[(k4 * 4 + 1) * 68 + tx * 4];
        float4 b2 = *(const float4*)&x1t[(k4 * 4 + 2) * 68 + tx * 4];
        float4 b3 = *(const float4*)&x1t[(k4 * 4 + 3) * 68 + tx * 4];
        #pragma unroll
        for (int di = 0; di < 8; di++) {
            float4 a = *(const float4*)&x0s[(ty * 8 + di) * 68 + k4 * 4];
            acc4[di].x += a.x * b0.x + a.y * b1.x + a.z * b2.x + a.w * b3.x;
            acc4[di].y += a.x * b0.y + a.y * b1.y + a.z * b2.y + a.w * b3.y;
            acc4[di].z += a.x * b0.z + a.y * b1.z + a.z * b2.z + a.w * b3.z;
            acc4[di].w += a.x * b0.w + a.y * b1.w + a.z * b2.w + a.w * b3.w;
        }
    }

    int ib = b * NN + i0 + ty * 8;
    float4 s1 = *(const float4*)&sq1[b * NN + j0 + tx * 4];

    if (WRITE) {
        float mv = sqrtf(__uint_as_float(maxd[b])) + EPS_NORM;
        #pragma unroll
        for (int di = 0; di < 8; di++) {
            float s0 = sq0[ib + di];
            float4 o;
            o.x = expf(-((sqrtf(fmaxf(s0 + s1.x - 2.f * acc4[di].x, 0.f)) / mv) / REGv));
            o.y = expf(-((sqrtf(fmaxf(s0 + s1.y - 2.f * acc4[di].y, 0.f)) / mv) / REGv));
            o.z = expf(-((sqrtf(fmaxf(s0 + s1.z - 2.f * acc4[di].z, 0.f)) / mv) / REGv));
            o.w = expf(-((sqrtf(fmaxf(s0 + s1.w - 2.f * acc4[di].w, 0.f)) / mv) / REGv));
            *(float4*)&Kd[(size_t)(ib + di) * NN + j0 + tx * 4] = o;
        }
    } else {
        float lm = 0.0f;
        #pragma unroll
        for (int di = 0; di < 8; di++) {
            float s0 = sq0[ib + di];
            lm = fmaxf(lm, fmaxf(s0 + s1.x - 2.f * acc4[di].x, 0.f));
            lm = fmaxf(lm, fmaxf(s0 + s1.y - 2.f * acc4[di].y, 0.f));
            lm = fmaxf(lm, fmaxf(s0 + s1.z - 2.f * acc4[di].z, 0.f));
            lm = fmaxf(lm, fmaxf(s0 + s1.w - 2.f * acc4[di].w, 0.f));
        }
        #pragma unroll
        for (int off = 32; off; off >>= 1) lm = fmaxf(lm, __shfl_xor(lm, off));
        if ((t & 63) == 0) wred[t >> 6] = lm;
        __syncthreads();
        if (t == 0) {
            float m = fmaxf(fmaxf(wred[0], wred[1]), fmaxf(wred[2], wred[3]));
            atomicMax(&maxd[b], __float_as_uint(m));  // d2 >= 0: uint cmp == float cmp
        }
    }
}

// ---------------- hand-rolled grid barrier (256 co-resident blocks) ----------------
__device__ __forceinline__ void gbar(unsigned* c, int t) {
    __syncthreads();   // drain per-wave stores before arrive
    if (t == 0) {
        __threadfence();                 // release (agent scope)
        atomicAdd(c, 1u);
        while (__hip_atomic_load(c, __ATOMIC_RELAXED, __HIP_MEMORY_SCOPE_AGENT) < GRID_P)
            __builtin_amdgcn_s_sleep(1);
        __threadfence();                 // acquire
    }
    __syncthreads();
}

// ---------------- persistent Sinkhorn: K resident in VGPR+LDS for all 50 iters ----------------
// 256 blocks x 512 threads, 1 block/CU (LDS 152 KB). Block q: batch b=q>>5, rows g*64..g*64+63.
// Wave w owns rows w*8..w*8+7: rows 0-5 in 48 f4 VGPRs (asm-pinned), rows 6-7 in LDS.
// Lane l owns f4-columns {k*64+l : k=0..7}.
__global__ __launch_bounds__(512) __attribute__((amdgpu_waves_per_eu(2, 2)))
void persist_k(const float* __restrict__ Kd,
               float* __restrict__ partial,
               float* __restrict__ vglob,
               unsigned* __restrict__ bar,
               int* __restrict__ out) {
    __shared__ f4 Kl4[16 * 512];   // 128 KB: 16 LDS-resident K rows
    __shared__ f4 vbuf4[512];      // 8 KB
    __shared__ f4 s0buf[512];      // 8 KB: sigma merge waves 0-3 / vred scratch
    __shared__ f4 s1buf[512];      // 8 KB: sigma merge waves 4-7

    const int t = threadIdx.x;
    const int l = t & 63;
    const int w = t >> 6;
    const int q = blockIdx.x;
    const int b = q >> 5;
    const int g = q & 31;

    const f4* Kg = (const f4*)Kd + (size_t)(b * NN + g * 64 + w * 8) * 512;

    // stage LDS rows (r=6,7)
    #pragma unroll
    for (int rr = 0; rr < 2; rr++)
        #pragma unroll
        for (int k = 0; k < 8; k++)
            Kl4[(w * 2 + rr) * 512 + k * 64 + l] = Kg[(size_t)(6 + rr) * 512 + k * 64 + l];

    // stage register rows (r=0..5): 192 VGPRs, pinned live via asm
    f4 Kreg[6][8];
    #pragma unroll
    for (int r = 0; r < 6; r++)
        #pragma unroll
        for (int k = 0; k < 8; k++) {
            Kreg[r][k] = Kg[(size_t)r * 512 + k * 64 + l];
            KEEP(Kreg[r][k]);
        }

    vbuf4[t] = (f4){1.0f / NN, 1.0f / NN, 1.0f / NN, 1.0f / NN};

    const int kb6 = (w * 2) * 512 + l;
    const int kb7 = kb6 + 512;

    float u[8];

    for (int it = 0; it < NUM_ITERS; ++it) {
        __syncthreads();   // vbuf ready

        // ---- phase A: row dots -> u ----
        float dp[8] = {0, 0, 0, 0, 0, 0, 0, 0};
        #pragma unroll
        for (int k = 0; k < 8; k++) {
            f4 vk = vbuf4[k * 64 + l];
            f4 c6 = Kl4[kb6 + k * 64];
            f4 c7 = Kl4[kb7 + k * 64];
            #pragma unroll
            for (int r = 0; r < 6; r++) dp[r] += dotf4(Kreg[r][k], vk);
            dp[6] += dotf4(c6, vk);
            dp[7] += dotf4(c7, vk);
        }
        #pragma unroll
        for (int r = 0; r < 8; r++) {
            float s = dp[r];
            #pragma unroll
            for (int off = 32; off; off >>= 1) s += __shfl_xor(s, off);
            u[r] = 1.0f / (s + EPS_SINK);
        }

        // ---- phase B: sigma accumulated directly into LDS, serialized per wave-group ----
        f4* mybuf = (w < 4) ? s0buf : s1buf;
        const int ws = w & 3;
        #pragma unroll
        for (int step = 0; step < 4; step++) {
            if (ws == step) {
                #pragma unroll
                for (int k = 0; k < 8; k++) {
                    int idx = k * 64 + l;
                    f4 cur = (step == 0) ? (f4){0.f, 0.f, 0.f, 0.f} : mybuf[idx];
                    f4 c6 = Kl4[kb6 + k * 64];
                    f4 c7 = Kl4[kb7 + k * 64];
                    #pragma unroll
                    for (int r = 0; r < 6; r++) cur = fmaf4(u[r], Kreg[r][k], cur);
                    cur = fmaf4(u[6], c6, cur);
                    cur = fmaf4(u[7], c7, cur);
                    mybuf[idx] = cur;
                }
            }
            __syncthreads();
        }

        // ---- write block partial (8 KB) ----
        {
            f4 pt = s0buf[t] + s1buf[t];
            ((f4*)partial)[(size_t)(b * 32 + g) * 512 + t] = pt;
        }
        gbar(&bar[2 * it], t);

        // ---- distributed v-reduce: block q -> 16 f4 of vglob ----
        {
            int c4 = g * 16 + (t & 15);
            int prow = t >> 4;     // 0..31
            f4 pv = ((const f4*)partial)[(size_t)(b * 32 + prow) * 512 + c4];
            #pragma unroll
            for (int off = 16; off <= 32; off <<= 1) {
                pv.x += __shfl_xor(pv.x, off);
                pv.y += __shfl_xor(pv.y, off);
                pv.z += __shfl_xor(pv.z, off);
                pv.w += __shfl_xor(pv.w, off);
            }
            if (l < 16) s0buf[w * 16 + l] = pv;
            __syncthreads();
            if (t < 16) {
                f4 s = s0buf[t];
                #pragma unroll
                for (int ww = 1; ww < 8; ww++) s += s0buf[ww * 16 + t];
                f4 vv;
                vv.x = 1.0f / (s.x + EPS_SINK);
                vv.y = 1.0f / (s.y + EPS_SINK);
                vv.z = 1.0f / (s.z + EPS_SINK);
                vv.w = 1.0f / (s.w + EPS_SINK);
                ((f4*)vglob)[q * 16 + t] = vv;
            }
        }
        gbar(&bar[2 * it + 1], t);

        // ---- reload v for this batch ----
        vbuf4[t] = ((const f4*)vglob)[b * 512 + t];
    }
    __syncthreads();

    // ---- argmax of P = (u*K)*v per row (numpy first-occurrence tie-break) ----
    #pragma unroll
    for (int r = 0; r < 8; r++) {
        float best = -1.0f;
        int bi = 0;
        #pragma unroll
        for (int k = 0; k < 8; k++) {
            f4 vk = vbuf4[k * 64 + l];
            f4 kr;
            if (r < 6) kr = Kreg[r][k];
            else kr = Kl4[(r == 6 ? kb6 : kb7) + k * 64];
            f4 p;
            p.x = (u[r] * kr.x) * vk.x;
            p.y = (u[r] * kr.y) * vk.y;
            p.z = (u[r] * kr.z) * vk.z;
            p.w = (u[r] * kr.w) * vk.w;
            int j0 = k * 256 + l * 4;
            if (p.x > best) { best = p.x; bi = j0; }
            if (p.y > best) { best = p.y; bi = j0 + 1; }
            if (p.z > best) { best = p.z; bi = j0 + 2; }
            if (p.w > best) { best = p.w; bi = j0 + 3; }
        }
        #pragma unroll
        for (int off = 32; off; off >>= 1) {
            float ov = __shfl_xor(best, off);
            int oi = __shfl_xor(bi, off);
            if (ov > best || (ov == best && oi < bi)) { best = ov; bi = oi; }
        }
        if (l == 0) out[b * NN + g * 64 + w * 8 + r] = bi;
    }
}

extern "C" void kernel_launch(void* const* d_in, const int* in_sizes, int n_in,
                              void* d_out, int out_size, void* d_ws, size_t ws_size,
                              hipStream_t stream) {
    const float* x0 = (const float*)d_in[0];
    const float* x1 = (const float*)d_in[1];
    int* out = (int*)d_out;
    char* ws = (char*)d_ws;

    // ws layout (bytes)
    float* Kd      = (float*)(ws + 0ull);                 // 134217728
    float* partial = (float*)(ws + 134217728ull);         // 2097152
    float* vglob   = (float*)(ws + 136314880ull);         // 65536
    float* sq0     = (float*)(ws + 136380416ull);         // 65536
    float* sq1     = (float*)(ws + 136445952ull);         // 65536
    unsigned* maxd = (unsigned*)(ws + 136511488ull);      // 32
    unsigned* bar  = (unsigned*)(ws + 136511520ull);      // 512

    init_k<<<1, 256, 0, stream>>>(maxd, bar);
    sq_k<<<8192, 256, 0, stream>>>(x0, x1, sq0, sq1);
    distc_k<0><<<4096, 256, 0, stream>>>(x0, x1, sq0, sq1, Kd, maxd);
    distc_k<1><<<4096, 256, 0, stream>>>(x0, x1, sq0, sq1, Kd, maxd);
    persist_k<<<256, 512, 0, stream>>>(Kd, partial, vglob, bar, out);
}